// Round 1
// baseline (17346.512 us; speedup 1.0000x reference)
//
#include <hip/hip_runtime.h>
#include <math.h>

// ---------------- constants ----------------
#define B_   128
#define S_   120
#define T_   120
#define HENC 256
#define HDEC 512
#define VCMP 100

// workspace layout (float offsets)
#define OFF_EMBGI_F   0          // 100*768
#define OFF_EMBGI_B   76800      // 100*768
#define OFF_EMBGI_D   153600     // 100*1536
#define OFF_HENC      307200     // [dir][pp][128][256] = 2*2*128*256
#define OFF_HDEC      438272     // [pp][3][128][512]   = 2*3*128*512
#define OFF_HQP       831488     // [4][128][512]
#define OFF_CTX       1093632    // [128][512]
#define OFF_GIP       1159168    // [4][128][1536]
#define OFF_GHP       1945600    // [4][128][1536]
#define OFF_ENCOUT    2732032    // [128][120][512]
#define OFF_ENCATT    10596352   // [128][120][512]
#define WS_FLOATS     18460672   // ~73.9 MB

#define PSTRIDE_D 196608   // 128*1536 (gi/gh part stride, also enc gh slot stride)
#define PSTRIDE_Q 65536    // 128*512

__device__ __forceinline__ float sigm(float x)      { return 1.0f / (1.0f + __expf(-x)); }
__device__ __forceinline__ float tanh_fast(float x) { return 1.0f - 2.0f / (1.0f + __expf(2.0f * x)); }

__device__ __forceinline__ float wred_sum(float v) {
#pragma unroll
  for (int m = 32; m > 0; m >>= 1) v += __shfl_xor(v, m);
  return v;
}
__device__ __forceinline__ float wred_max(float v) {
#pragma unroll
  for (int m = 32; m > 0; m >>= 1) v = fmaxf(v, __shfl_xor(v, m));
  return v;
}

// ---------------- prep kernels ----------------
__global__ void k_zero(float* p, int n) {
  int i = blockIdx.x * blockDim.x + threadIdx.x;
  if (i < n) p[i] = 0.0f;
}

// emb_gi_enc[v][j] = bih[j] + sum_e emb[v][e]*Wih[j][e]   (E=5)
__global__ void k_embgi_enc(const float* emb, const float* Wf, const float* bf,
                            const float* Wb, const float* bb, float* outf, float* outb) {
  int idx = blockIdx.x * blockDim.x + threadIdx.x;  // < 76800
  const float* W  = blockIdx.y ? Wb : Wf;
  const float* bi = blockIdx.y ? bb : bf;
  float* o        = blockIdx.y ? outb : outf;
  int v = idx / 768, j = idx % 768;
  float a = bi[j];
#pragma unroll
  for (int e = 0; e < 5; e++) a = fmaf(emb[v * 5 + e], W[j * 5 + e], a);
  o[idx] = a;
}

// emb_gi_dec[v][j] = bih0[j] + sum_{e<128} emb_dec[v][e]*Wih0[j][e]  (ld 640)
__global__ void k_embgi_dec(const float* emb, const float* Wih0, const float* bih0, float* out) {
  int idx = blockIdx.x * blockDim.x + threadIdx.x;  // < 153600
  int v = idx / 1536, j = idx % 1536;
  float a = bih0[j];
  const float4* er = (const float4*)(emb + v * 128);
  const float4* wr = (const float4*)(Wih0 + (size_t)j * 640);
#pragma unroll 8
  for (int e = 0; e < 32; e++) {
    float4 ev = er[e], wv = wr[e];
    a = fmaf(ev.x, wv.x, a); a = fmaf(ev.y, wv.y, a);
    a = fmaf(ev.z, wv.z, a); a = fmaf(ev.w, wv.w, a);
  }
  out[idx] = a;
}

// ---------------- GEMM: C = A @ W^T  (partials over K splits) ----------------
struct GemmJob {
  const float* A; const float* W; float* C; const float* bias;
  int lda, ldw, N;
};

// 64x64 tile, micro 4x4, TK=16
__global__ __launch_bounds__(256) void k_gemm64(GemmJob ja, GemmJob jb, int splits, int Kc, int Cstride) {
  GemmJob jj = ((int)blockIdx.z < splits) ? ja : jb;
  int sp = blockIdx.z % splits;
  int k0 = sp * Kc;
  float* C = jj.C + (size_t)sp * Cstride;
  int tid = threadIdx.x;
  int tx = tid & 15, ty = tid >> 4;
  int m0 = blockIdx.y * 64, n0 = blockIdx.x * 64;
  __shared__ float As[16][68];
  __shared__ float Ws[16][68];
  float acc[4][4] = {};
  int r = tid >> 2, c = tid & 3;
  const float* Ap = jj.A + (size_t)(m0 + r) * jj.lda + k0 + c * 4;
  const float* Wp = jj.W + (size_t)(n0 + r) * jj.ldw + k0 + c * 4;
  for (int kt = 0; kt < Kc; kt += 16) {
    float4 av = *(const float4*)(Ap + kt);
    float4 wv = *(const float4*)(Wp + kt);
    __syncthreads();
    As[c * 4 + 0][r] = av.x; As[c * 4 + 1][r] = av.y; As[c * 4 + 2][r] = av.z; As[c * 4 + 3][r] = av.w;
    Ws[c * 4 + 0][r] = wv.x; Ws[c * 4 + 1][r] = wv.y; Ws[c * 4 + 2][r] = wv.z; Ws[c * 4 + 3][r] = wv.w;
    __syncthreads();
#pragma unroll
    for (int kk = 0; kk < 16; kk++) {
      float4 a = *(const float4*)&As[kk][ty * 4];
      float4 w = *(const float4*)&Ws[kk][tx * 4];
      float am[4] = {a.x, a.y, a.z, a.w}, wn[4] = {w.x, w.y, w.z, w.w};
#pragma unroll
      for (int i = 0; i < 4; i++)
#pragma unroll
        for (int j2 = 0; j2 < 4; j2++) acc[i][j2] = fmaf(am[i], wn[j2], acc[i][j2]);
    }
  }
  int N = jj.N;
  float bv[4] = {0, 0, 0, 0};
  if (jj.bias) {
#pragma unroll
    for (int j2 = 0; j2 < 4; j2++) bv[j2] = jj.bias[n0 + tx * 4 + j2];
  }
#pragma unroll
  for (int i = 0; i < 4; i++) {
    float4 v = {acc[i][0] + bv[0], acc[i][1] + bv[1], acc[i][2] + bv[2], acc[i][3] + bv[3]};
    *(float4*)(C + (size_t)(m0 + ty * 4 + i) * N + n0 + tx * 4) = v;
  }
}

// 128x128 tile, micro 8x8 (split 4+4 to stay conflict-free), TK=16
__global__ __launch_bounds__(256) void k_gemm128(GemmJob ja, GemmJob jb, int splits, int Kc, int Cstride) {
  GemmJob jj = ((int)blockIdx.z < splits) ? ja : jb;
  int sp = blockIdx.z % splits;
  int k0 = sp * Kc;
  float* C = jj.C + (size_t)sp * Cstride;
  int tid = threadIdx.x;
  int tx = tid & 15, ty = tid >> 4;
  int m0 = blockIdx.y * 128, n0 = blockIdx.x * 128;
  __shared__ float As[16][132];
  __shared__ float Ws[16][132];
  float acc[8][8] = {};
  for (int kt = 0; kt < Kc; kt += 16) {
    float4 av[2], wv[2];
#pragma unroll
    for (int h = 0; h < 2; h++) {
      int idx = tid + h * 256;
      int r = idx >> 2, c = idx & 3;
      av[h] = *(const float4*)(jj.A + (size_t)(m0 + r) * jj.lda + k0 + kt + c * 4);
      wv[h] = *(const float4*)(jj.W + (size_t)(n0 + r) * jj.ldw + k0 + kt + c * 4);
    }
    __syncthreads();
#pragma unroll
    for (int h = 0; h < 2; h++) {
      int idx = tid + h * 256;
      int r = idx >> 2, c = idx & 3;
      As[c * 4 + 0][r] = av[h].x; As[c * 4 + 1][r] = av[h].y; As[c * 4 + 2][r] = av[h].z; As[c * 4 + 3][r] = av[h].w;
      Ws[c * 4 + 0][r] = wv[h].x; Ws[c * 4 + 1][r] = wv[h].y; Ws[c * 4 + 2][r] = wv[h].z; Ws[c * 4 + 3][r] = wv[h].w;
    }
    __syncthreads();
#pragma unroll
    for (int kk = 0; kk < 16; kk++) {
      float4 a0 = *(const float4*)&As[kk][ty * 4];
      float4 a1 = *(const float4*)&As[kk][ty * 4 + 64];
      float4 w0 = *(const float4*)&Ws[kk][tx * 4];
      float4 w1 = *(const float4*)&Ws[kk][tx * 4 + 64];
      float am[8] = {a0.x, a0.y, a0.z, a0.w, a1.x, a1.y, a1.z, a1.w};
      float wn[8] = {w0.x, w0.y, w0.z, w0.w, w1.x, w1.y, w1.z, w1.w};
#pragma unroll
      for (int i = 0; i < 8; i++)
#pragma unroll
        for (int j2 = 0; j2 < 8; j2++) acc[i][j2] = fmaf(am[i], wn[j2], acc[i][j2]);
    }
  }
  int N = jj.N;
  float bv[8] = {0, 0, 0, 0, 0, 0, 0, 0};
  if (jj.bias) {
#pragma unroll
    for (int j2 = 0; j2 < 4; j2++) {
      bv[j2]     = jj.bias[n0 + tx * 4 + j2];
      bv[4 + j2] = jj.bias[n0 + 64 + tx * 4 + j2];
    }
  }
#pragma unroll
  for (int i = 0; i < 8; i++) {
    int m = m0 + ((i < 4) ? (ty * 4 + i) : (64 + ty * 4 + (i - 4)));
    float4 v0 = {acc[i][0] + bv[0], acc[i][1] + bv[1], acc[i][2] + bv[2], acc[i][3] + bv[3]};
    float4 v1 = {acc[i][4] + bv[4], acc[i][5] + bv[5], acc[i][6] + bv[6], acc[i][7] + bv[7]};
    *(float4*)(C + (size_t)m * N + n0 + tx * 4) = v0;
    *(float4*)(C + (size_t)m * N + n0 + 64 + tx * 4) = v1;
  }
}

// ---------------- encoder gate ----------------
__global__ void k_gate_enc(const float* ghP, const float* tabf, const float* tabb,
                           const float* bhhf, const float* bhhb, const int* tgts,
                           const float* hfc, float* hfn, const float* hbc, float* hbn,
                           float* enc_out, int t) {
  int g = blockIdx.x * blockDim.x + threadIdx.x;  // 2*128*256 = 65536
  int d = g >> 15, rem = g & 32767, b = rem >> 8, j = rem & 255;
  int sidx = d ? (S_ - 1 - t) : t;
  int tok = tgts[b * S_ + sidx];
  const float* gh  = ghP + (size_t)(d * 2) * PSTRIDE_D + b * 768;
  const float* bh  = d ? bhhb : bhhf;
  const float* tab = (d ? tabb : tabf) + (size_t)tok * 768;
  float hr  = gh[j]       + gh[PSTRIDE_D + j]       + bh[j];
  float hz  = gh[j + 256] + gh[PSTRIDE_D + j + 256] + bh[j + 256];
  float hnn = gh[j + 512] + gh[PSTRIDE_D + j + 512] + bh[j + 512];
  float rr = sigm(tab[j] + hr);
  float zz = sigm(tab[j + 256] + hz);
  float nn = tanh_fast(tab[j + 512] + rr * hnn);
  const float* hc = d ? hbc : hfc;
  float*       hx = d ? hbn : hfn;
  float h0 = hc[b * 256 + j];
  float h2 = (1.0f - zz) * nn + zz * h0;
  hx[b * 256 + j] = h2;
  enc_out[((size_t)b * S_ + sidx) * 512 + d * 256 + j] = h2;
}

__global__ void k_h0init(const float* hf, const float* hb, float* h0) {
  int g = blockIdx.x * blockDim.x + threadIdx.x;  // 65536
  int b = g >> 9, j = g & 511;
  h0[g] = (j < 256) ? hf[b * 256 + j] : hb[b * 256 + (j - 256)];
}

// ---------------- decoder attention (scores + softmax + ctx) ----------------
__global__ __launch_bounds__(256) void k_att_ctx(const float* hqP, const float* enc_att,
                                                 const float* enc_out, const float* av,
                                                 float* ctx) {
  int b = blockIdx.x;
  __shared__ float hq[512];
  __shared__ float vs[512];
  __shared__ float sc[128];
  __shared__ float red[8];
  int tid = threadIdx.x, w = tid >> 6, lane = tid & 63;
  for (int d = tid; d < 512; d += 256) {
    hq[d] = hqP[b * 512 + d] + hqP[PSTRIDE_Q + b * 512 + d] +
            hqP[2 * PSTRIDE_Q + b * 512 + d] + hqP[3 * PSTRIDE_Q + b * 512 + d];
    vs[d] = av[d];
  }
  __syncthreads();
  for (int i = 0; i < 30; i++) {
    int s = w + 4 * i;
    const float4* ea = (const float4*)(enc_att + ((size_t)b * S_ + s) * 512) + lane * 2;
    float4 e0 = ea[0], e1 = ea[1];
    int d0 = lane * 8;
    float a;
    a  = vs[d0 + 0] * tanh_fast(e0.x + hq[d0 + 0]);
    a += vs[d0 + 1] * tanh_fast(e0.y + hq[d0 + 1]);
    a += vs[d0 + 2] * tanh_fast(e0.z + hq[d0 + 2]);
    a += vs[d0 + 3] * tanh_fast(e0.w + hq[d0 + 3]);
    a += vs[d0 + 4] * tanh_fast(e1.x + hq[d0 + 4]);
    a += vs[d0 + 5] * tanh_fast(e1.y + hq[d0 + 5]);
    a += vs[d0 + 6] * tanh_fast(e1.z + hq[d0 + 6]);
    a += vs[d0 + 7] * tanh_fast(e1.w + hq[d0 + 7]);
    a = wred_sum(a);
    if (lane == 0) sc[s] = a;
  }
  __syncthreads();
  float x = (tid < S_) ? sc[tid] : -1e30f;
  float mx = wred_max(x);
  if (lane == 0) red[w] = mx;
  __syncthreads();
  mx = fmaxf(fmaxf(red[0], red[1]), fmaxf(red[2], red[3]));
  float e = (tid < S_) ? __expf(x - mx) : 0.0f;
  float sm = wred_sum(e);
  if (lane == 0) red[4 + w] = sm;
  __syncthreads();
  float inv = 1.0f / (red[4] + red[5] + red[6] + red[7]);
  if (tid < S_) sc[tid] = e * inv;
  __syncthreads();
  for (int h = tid; h < 512; h += 256) {
    float cacc = 0.0f;
    const float* eo = enc_out + (size_t)b * S_ * 512 + h;
#pragma unroll 4
    for (int s = 0; s < S_; s++) cacc = fmaf(sc[s], eo[(size_t)s * 512], cacc);
    ctx[b * 512 + h] = cacc;
  }
}

// ---------------- decoder gate ----------------
__global__ void k_gate_dec(const float* giP, const float* ghP, const float* gtab,
                           const int* cmps, int t, const float* bih, const float* bhh,
                           const float* hp, float* hn) {
  int g = blockIdx.x * blockDim.x + threadIdx.x;  // 65536
  int b = g >> 9, j = g & 511;
  int base = b * 1536 + j;
  float gr  = giP[base]        + giP[PSTRIDE_D + base]        + giP[2 * PSTRIDE_D + base]        + giP[3 * PSTRIDE_D + base];
  float gz  = giP[base + 512]  + giP[PSTRIDE_D + base + 512]  + giP[2 * PSTRIDE_D + base + 512]  + giP[3 * PSTRIDE_D + base + 512];
  float gn  = giP[base + 1024] + giP[PSTRIDE_D + base + 1024] + giP[2 * PSTRIDE_D + base + 1024] + giP[3 * PSTRIDE_D + base + 1024];
  float hr  = ghP[base]        + ghP[PSTRIDE_D + base]        + ghP[2 * PSTRIDE_D + base]        + ghP[3 * PSTRIDE_D + base]        + bhh[j];
  float hz  = ghP[base + 512]  + ghP[PSTRIDE_D + base + 512]  + ghP[2 * PSTRIDE_D + base + 512]  + ghP[3 * PSTRIDE_D + base + 512]  + bhh[j + 512];
  float hnn = ghP[base + 1024] + ghP[PSTRIDE_D + base + 1024] + ghP[2 * PSTRIDE_D + base + 1024] + ghP[3 * PSTRIDE_D + base + 1024] + bhh[j + 1024];
  float er, ez, en;
  if (gtab) {
    int tok = (t == 0) ? 0 : cmps[b * T_ + (t - 1)];
    const float* row = gtab + (size_t)tok * 1536;
    er = row[j]; ez = row[j + 512]; en = row[j + 1024];
  } else {
    er = bih[j]; ez = bih[j + 512]; en = bih[j + 1024];
  }
  float rr = sigm(gr + er + hr);
  float zz = sigm(gz + ez + hz);
  float nn = tanh_fast(gn + en + rr * hnn);
  float h0 = hp[b * 512 + j];
  hn[b * 512 + j] = (1.0f - zz) * nn + zz * h0;
}

// ---------------- output logits + log_softmax ----------------
__global__ __launch_bounds__(256) void k_out(const float* h2, const float* oW, const float* ob,
                                             float* out, int t) {
  int b = blockIdx.x;
  __shared__ float hs[512];
  __shared__ float lg[104];
  __shared__ float red[8];
  int tid = threadIdx.x, w = tid >> 6, lane = tid & 63;
  for (int d = tid; d < 512; d += 256) hs[d] = h2[b * 512 + d];
  __syncthreads();
  for (int i = 0; i < 25; i++) {
    int n = w + 4 * i;  // 4 waves x 25 = 100
    const float4* wr = (const float4*)(oW + (size_t)n * 512) + lane * 2;
    float4 w0 = wr[0], w1 = wr[1];
    const float* hp = &hs[lane * 8];
    float a = w0.x * hp[0] + w0.y * hp[1] + w0.z * hp[2] + w0.w * hp[3] +
              w1.x * hp[4] + w1.y * hp[5] + w1.z * hp[6] + w1.w * hp[7];
    a = wred_sum(a);
    if (lane == 0) lg[n] = a + ob[n];
  }
  __syncthreads();
  float x = (tid < VCMP) ? lg[tid] : -1e30f;
  float mx = wred_max(x);
  if (lane == 0) red[w] = mx;
  __syncthreads();
  mx = fmaxf(fmaxf(red[0], red[1]), fmaxf(red[2], red[3]));
  float e = (tid < VCMP) ? __expf(x - mx) : 0.0f;
  float sm = wred_sum(e);
  if (lane == 0) red[4 + w] = sm;
  __syncthreads();
  float lse = mx + logf(red[4] + red[5] + red[6] + red[7]);
  if (tid < VCMP) out[((size_t)b * T_ + t) * VCMP + tid] = x - lse;
}

// ---------------- host ----------------
extern "C" void kernel_launch(void* const* d_in, const int* in_sizes, int n_in,
                              void* d_out, int out_size, void* d_ws, size_t ws_size,
                              hipStream_t stream) {
  (void)in_sizes; (void)n_in; (void)out_size; (void)ws_size;
  const int*   tgts    = (const int*)d_in[0];
  const int*   cmps    = (const int*)d_in[1];
  const float* emb_enc = (const float*)d_in[2];
  const float* eWih_f  = (const float*)d_in[3];
  const float* eWhh_f  = (const float*)d_in[4];
  const float* ebih_f  = (const float*)d_in[5];
  const float* ebhh_f  = (const float*)d_in[6];
  const float* eWih_b  = (const float*)d_in[7];
  const float* eWhh_b  = (const float*)d_in[8];
  const float* ebih_b  = (const float*)d_in[9];
  const float* ebhh_b  = (const float*)d_in[10];
  const float* emb_dec = (const float*)d_in[11];
  const float* attn_W  = (const float*)d_in[12];
  const float* attn_b  = (const float*)d_in[13];
  const float* attn_v  = (const float*)d_in[14];
  const float* dWih0   = (const float*)d_in[15];
  const float* dWhh0   = (const float*)d_in[16];
  const float* dbih0   = (const float*)d_in[17];  (void)dbih0; // folded into emb_gi_d
  const float* dbhh0   = (const float*)d_in[18];
  const float* dWih1   = (const float*)d_in[19];
  const float* dWhh1   = (const float*)d_in[20];
  const float* dbih1   = (const float*)d_in[21];
  const float* dbhh1   = (const float*)d_in[22];
  const float* dWih2   = (const float*)d_in[23];
  const float* dWhh2   = (const float*)d_in[24];
  const float* dbih2   = (const float*)d_in[25];
  const float* dbhh2   = (const float*)d_in[26];
  const float* out_W   = (const float*)d_in[27];
  const float* out_b   = (const float*)d_in[28];
  float* out = (float*)d_out;
  float* ws  = (float*)d_ws;

  float* emb_gi_f = ws + OFF_EMBGI_F;
  float* emb_gi_b = ws + OFF_EMBGI_B;
  float* emb_gi_d = ws + OFF_EMBGI_D;
  float* h_enc    = ws + OFF_HENC;   // [dir][pp][128][256]: dir*65536 + pp*32768
  float* h_dec    = ws + OFF_HDEC;   // [pp][L][128][512]:  pp*196608 + L*65536
  float* hqP      = ws + OFF_HQP;
  float* ctx      = ws + OFF_CTX;
  float* giP      = ws + OFF_GIP;
  float* ghP      = ws + OFF_GHP;
  float* enc_out  = ws + OFF_ENCOUT;
  float* enc_att  = ws + OFF_ENCATT;

  // prep
  k_embgi_enc<<<dim3(300, 2), 256, 0, stream>>>(emb_enc, eWih_f, ebih_f, eWih_b, ebih_b, emb_gi_f, emb_gi_b);
  k_embgi_dec<<<600, 256, 0, stream>>>(emb_dec, dWih0, dbih0, emb_gi_d);
  {
    int nz = 2 * 2 * B_ * HENC + 2 * 3 * B_ * HDEC;  // h_enc + h_dec contiguous
    k_zero<<<(nz + 255) / 256, 256, 0, stream>>>(h_enc, nz);
  }

  // ---- encoder: 120 steps, forward+backward in one launch pair ----
  for (int t = 0; t < S_; t++) {
    int cur = t & 1, nxt = cur ^ 1;
    GemmJob ja = {h_enc + 0 * 65536 + cur * 32768, eWhh_f, giP, nullptr, 256, 256, 768};
    GemmJob jb = {h_enc + 1 * 65536 + cur * 32768, eWhh_b, giP + 2 * PSTRIDE_D, nullptr, 256, 256, 768};
    k_gemm64<<<dim3(12, 2, 4), 256, 0, stream>>>(ja, jb, 2, 128, PSTRIDE_D);
    k_gate_enc<<<256, 256, 0, stream>>>(giP, emb_gi_f, emb_gi_b, ebhh_f, ebhh_b, tgts,
                                        h_enc + cur * 32768, h_enc + nxt * 32768,
                                        h_enc + 65536 + cur * 32768, h_enc + 65536 + nxt * 32768,
                                        enc_out, t);
  }
  // final hidden states live in pp=0 (120 is even)
  k_h0init<<<256, 256, 0, stream>>>(h_enc, h_enc + 65536, h_dec);

  // ---- hoisted attention encoder part: enc_att = enc_out @ Ue^T + attn_b ----
  {
    GemmJob ja = {enc_out, attn_W + 512, enc_att, attn_b, 512, 1024, 512};
    k_gemm128<<<dim3(4, 120, 1), 256, 0, stream>>>(ja, ja, 1, 512, 0);
  }

  // ---- decoder: 120 steps ----
  for (int t = 0; t < T_; t++) {
    int cur = t & 1, nxt = cur ^ 1;
    float* h0c = h_dec + cur * 196608;
    float* h1c = h0c + 65536;
    float* h2c = h0c + 131072;
    float* h0n = h_dec + nxt * 196608;
    float* h1n = h0n + 65536;
    float* h2n = h0n + 131072;
    (void)h2c;

    GemmJob jq = {h0c, attn_W, hqP, nullptr, 512, 1024, 512};
    k_gemm64<<<dim3(8, 2, 4), 256, 0, stream>>>(jq, jq, 4, 128, PSTRIDE_Q);
    k_att_ctx<<<128, 256, 0, stream>>>(hqP, enc_att, enc_out, attn_v, ctx);

    // layer 0: gi = ctx @ Wih0[:,128:]^T (+emb table in gate); gh = h0 @ Whh0^T
    GemmJob g0a = {ctx, dWih0 + 128, giP, nullptr, 512, 640, 1536};
    GemmJob g0b = {h0c, dWhh0, ghP, nullptr, 512, 512, 1536};
    k_gemm128<<<dim3(12, 1, 8), 256, 0, stream>>>(g0a, g0b, 4, 128, PSTRIDE_D);
    k_gate_dec<<<256, 256, 0, stream>>>(giP, ghP, emb_gi_d, cmps, t, nullptr, dbhh0, h0c, h0n);

    // layer 1
    GemmJob g1a = {h0n, dWih1, giP, nullptr, 512, 512, 1536};
    GemmJob g1b = {h1c, dWhh1, ghP, nullptr, 512, 512, 1536};
    k_gemm128<<<dim3(12, 1, 8), 256, 0, stream>>>(g1a, g1b, 4, 128, PSTRIDE_D);
    k_gate_dec<<<256, 256, 0, stream>>>(giP, ghP, nullptr, nullptr, t, dbih1, dbhh1, h1c, h1n);

    // layer 2
    GemmJob g2a = {h1n, dWih2, giP, nullptr, 512, 512, 1536};
    GemmJob g2b = {h2c, dWhh2, ghP, nullptr, 512, 512, 1536};
    k_gemm128<<<dim3(12, 1, 8), 256, 0, stream>>>(g2a, g2b, 4, 128, PSTRIDE_D);
    k_gate_dec<<<256, 256, 0, stream>>>(giP, ghP, nullptr, nullptr, t, dbih2, dbhh2, h2c, h2n);

    k_out<<<128, 256, 0, stream>>>(h2n, out_W, out_b, out, t);
  }
}

// Round 2
// 16867.392 us; speedup vs baseline: 1.0284x; 1.0284x over previous
//
#include <hip/hip_runtime.h>
#include <math.h>

// ---------------- constants ----------------
#define B_   128
#define S_   120
#define T_   120
#define VCMP 100

typedef _Float16 f16;
typedef _Float16 f16x8 __attribute__((ext_vector_type(8)));
typedef float f32x4 __attribute__((ext_vector_type(4)));

#define MFMA16(a,b,c) __builtin_amdgcn_mfma_f32_16x16x32_f16(a, b, c, 0, 0, 0)

// workspace layout (float offsets)
#define OFF_TAB_F    0          // [100][768] f32
#define OFF_TAB_B    76800
#define OFF_TAB_D    153600     // [100][1536] f32
#define OFF_HENC32   307200     // [dir][pp][128][256] f32
#define OFF_HENC16   438272     // same, f16 (131072 halfs)
#define OFF_HDEC32   503808     // [pp][3][128][512] f32
#define OFF_HDEC16   897024     // [pp][2][128][512] f16 (h0,h1)
#define OFF_CA       1028096    // [128][5120] f32  (hq | gh0 | gh1 | gh2)
#define OFF_CTX32    1683456    // [128][512] f32
#define OFF_CTX16    1748992    // [128][512] f16
#define OFF_H2ALL    1781760    // [121][128][512] f16 (slot t = h2 entering step t)
#define OFF_ENCOUT   5746688    // [128][120][512] f16
#define OFF_ENCATT   9678848    // [b*120+s][512] f16
#define OFF_LOGITS   13611008   // [15360][128] f32
#define OFF_WCAT     15577088   // [5120][512] f16: Ua | Whh0 | Whh1 | Whh2
#define OFF_WIH0C    16887808   // [1536][512] f16 (dWih0[:,128:])
#define OFF_WIH1     17281024   // [1536][512] f16
#define OFF_WIH2     17674240   // [1536][512] f16
#define OFF_UE       18067456   // [512][512] f16 (attn_W[:,512:])
#define OFF_EWHH     18198528   // [2][768][256] f16
#define OFF_OW       18395136   // [128][512] f16 (rows>=100 zero)
#define WS_FLOATS    18427904   // ~73.7 MB

__device__ __forceinline__ float sigm(float x)      { return 1.0f / (1.0f + __expf(-x)); }
__device__ __forceinline__ float tanh_fast(float x) { return 1.0f - 2.0f / (1.0f + __expf(2.0f * x)); }

__device__ __forceinline__ float wred_sum(float v) {
#pragma unroll
  for (int m = 32; m > 0; m >>= 1) v += __shfl_xor(v, m);
  return v;
}
__device__ __forceinline__ float wred_max(float v) {
#pragma unroll
  for (int m = 32; m > 0; m >>= 1) v = fmaxf(v, __shfl_xor(v, m));
  return v;
}

// ---------------- prep kernels ----------------
__global__ void k_zero(float* p, int n) {
  int i = blockIdx.x * blockDim.x + threadIdx.x;
  if (i < n) p[i] = 0.0f;
}

__global__ void k_cvt(const float* src, f16* dst, int rows, int cols, int ldsrc, int off) {
  int i = blockIdx.x * blockDim.x + threadIdx.x;
  if (i >= rows * cols) return;
  int r = i / cols, c = i - r * cols;
  dst[(size_t)r * cols + c] = (f16)src[(size_t)r * ldsrc + off + c];
}

// emb_gi_enc[v][j] = bih[j] + sum_e emb[v][e]*Wih[j][e]   (E=5)
__global__ void k_embgi_enc(const float* emb, const float* Wf, const float* bf,
                            const float* Wb, const float* bb, float* outf, float* outb) {
  int idx = blockIdx.x * blockDim.x + threadIdx.x;  // < 76800
  const float* W  = blockIdx.y ? Wb : Wf;
  const float* bi = blockIdx.y ? bb : bf;
  float* o        = blockIdx.y ? outb : outf;
  int v = idx / 768, j = idx % 768;
  float a = bi[j];
#pragma unroll
  for (int e = 0; e < 5; e++) a = fmaf(emb[v * 5 + e], W[j * 5 + e], a);
  o[idx] = a;
}

// emb_gi_dec[v][j] = bih0[j] + sum_{e<128} emb_dec[v][e]*Wih0[j][e]  (ld 640)
__global__ void k_embgi_dec(const float* emb, const float* Wih0, const float* bih0, float* out) {
  int idx = blockIdx.x * blockDim.x + threadIdx.x;  // < 153600
  int v = idx / 1536, j = idx % 1536;
  float a = bih0[j];
  const float4* er = (const float4*)(emb + v * 128);
  const float4* wr = (const float4*)(Wih0 + (size_t)j * 640);
#pragma unroll 8
  for (int e = 0; e < 32; e++) {
    float4 ev = er[e], wv = wr[e];
    a = fmaf(ev.x, wv.x, a); a = fmaf(ev.y, wv.y, a);
    a = fmaf(ev.z, wv.z, a); a = fmaf(ev.w, wv.w, a);
  }
  out[idx] = a;
}

__global__ void k_h0init(const float* hf, const float* hb, float* h32, f16* h16) {
  int g = blockIdx.x * blockDim.x + threadIdx.x;  // 65536
  int b = g >> 9, j = g & 511;
  float v = (j < 256) ? hf[b * 256 + j] : hb[b * 256 + (j - 256)];
  h32[g] = v; h16[g] = (f16)v;
}

// ---------------- MFMA warp-tile core ----------------
// block = 4 warps (2x2), block tile 64m x 64n (x NC chunks); warp tile 32x32.
// A: [M][ldA] f16 K-contig; W: [N(+chunks)][ldW] f16 K-contig. C[m][n] = sum_k A[m][k]W[n][k].
template<int NC>
__device__ __forceinline__ void gemm_core(const f16* A, int ldA, const f16* W, int ldW,
                                          int chunkRows, int K, int m0, int n0,
                                          int lane, int wm, int wn, f32x4 acc[2][2][NC]) {
  const f16* Ap0 = A + (size_t)(m0 + wm * 32 + (lane & 15)) * ldA + ((lane >> 4) << 3);
  const f16* Ap1 = Ap0 + (size_t)16 * ldA;
  const f16* Wp0 = W + (size_t)(n0 + wn * 32 + (lane & 15)) * ldW + ((lane >> 4) << 3);
  const f16* Wp1 = Wp0 + (size_t)16 * ldW;
#pragma unroll 2
  for (int k = 0; k < K; k += 32) {
    f16x8 a0 = *(const f16x8*)(Ap0 + k);
    f16x8 a1 = *(const f16x8*)(Ap1 + k);
#pragma unroll
    for (int c = 0; c < NC; c++) {
      const f16* w0 = Wp0 + (size_t)c * chunkRows * ldW + k;
      const f16* w1 = Wp1 + (size_t)c * chunkRows * ldW + k;
      f16x8 b0 = *(const f16x8*)w0;
      f16x8 b1 = *(const f16x8*)w1;
      acc[0][0][c] = MFMA16(a0, b0, acc[0][0][c]);
      acc[1][0][c] = MFMA16(a1, b0, acc[1][0][c]);
      acc[0][1][c] = MFMA16(a0, b1, acc[0][1][c]);
      acc[1][1][c] = MFMA16(a1, b1, acc[1][1][c]);
    }
  }
}

// ---------------- phase A: CA[128][5120] = [hq | gh0 | gh1 | gh2] ----------------
__global__ __launch_bounds__(256) void k_phaseA(const f16* h0, const f16* h1, const f16* h2,
                                                const f16* Wcat, float* CA) {
  int n0 = blockIdx.x * 64, m0 = blockIdx.y * 64;
  int tid = threadIdx.x, lane = tid & 63, w = tid >> 6, wm = w >> 1, wn = w & 1;
  const f16* A = (n0 < 2048) ? h0 : (n0 < 3584 ? h1 : h2);
  f32x4 acc[2][2][1] = {};
  gemm_core<1>(A, 512, Wcat, 512, 0, 512, m0, n0, lane, wm, wn, acc);
#pragma unroll
  for (int i = 0; i < 2; i++)
#pragma unroll
    for (int j = 0; j < 2; j++) {
      int mb = m0 + wm * 32 + i * 16 + ((lane >> 4) << 2);
      int n  = n0 + wn * 32 + j * 16 + (lane & 15);
#pragma unroll
      for (int r = 0; r < 4; r++) CA[(size_t)(mb + r) * 5120 + n] = acc[i][j][0][r];
    }
}

// ---------------- generic GEMM + bias (enc_att f16 out; logits f32 out) ----------------
template<bool OUT16>
__global__ __launch_bounds__(256) void k_gemm_bias(const f16* A, int ldA, const f16* W, int ldW,
                                                   const float* bias, int nbias, void* Cout,
                                                   int ldC, int K) {
  int n0 = blockIdx.x * 64, m0 = blockIdx.y * 64;
  int tid = threadIdx.x, lane = tid & 63, w = tid >> 6, wm = w >> 1, wn = w & 1;
  f32x4 acc[2][2][1] = {};
  gemm_core<1>(A, ldA, W, ldW, 0, K, m0, n0, lane, wm, wn, acc);
#pragma unroll
  for (int i = 0; i < 2; i++)
#pragma unroll
    for (int j = 0; j < 2; j++) {
      int mb = m0 + wm * 32 + i * 16 + ((lane >> 4) << 2);
      int n  = n0 + wn * 32 + j * 16 + (lane & 15);
      float bv = (bias && n < nbias) ? bias[n] : 0.0f;
#pragma unroll
      for (int r = 0; r < 4; r++) {
        float v = acc[i][j][0][r] + bv;
        if (OUT16) ((f16*)Cout)[(size_t)(mb + r) * ldC + n] = (f16)v;
        else       ((float*)Cout)[(size_t)(mb + r) * ldC + n] = v;
      }
    }
}

// ---------------- decoder layer: gi GEMM (3 chunks) + fused GRU gate ----------------
__global__ __launch_bounds__(256) void k_dec_layer(const f16* Ah, const f16* W3, const float* CA,
                                                   int ghoff, const float* tab, const int* cmps,
                                                   int t, const float* bih, const float* bhh,
                                                   const float* hprev, float* hout32, f16* hout16) {
  int n0 = blockIdx.x * 64, m0 = blockIdx.y * 64;
  int tid = threadIdx.x, lane = tid & 63, w = tid >> 6, wm = w >> 1, wn = w & 1;
  f32x4 acc[2][2][3] = {};
  gemm_core<3>(Ah, 512, W3, 512, 512, 512, m0, n0, lane, wm, wn, acc);
#pragma unroll
  for (int i = 0; i < 2; i++)
#pragma unroll
    for (int j = 0; j < 2; j++) {
      int mb = m0 + wm * 32 + i * 16 + ((lane >> 4) << 2);
      int n  = n0 + wn * 32 + j * 16 + (lane & 15);
#pragma unroll
      for (int r = 0; r < 4; r++) {
        int m = mb + r;
        const float* ghp = CA + (size_t)m * 5120 + ghoff + n;
        float hr  = ghp[0]    + bhh[n];
        float hz  = ghp[512]  + bhh[n + 512];
        float hnn = ghp[1024] + bhh[n + 1024];
        float er, ez, en;
        if (tab) {
          int tok = t ? cmps[m * T_ + (t - 1)] : 0;
          const float* row = tab + (size_t)tok * 1536;
          er = row[n]; ez = row[n + 512]; en = row[n + 1024];
        } else {
          er = bih[n]; ez = bih[n + 512]; en = bih[n + 1024];
        }
        float rr = sigm(acc[i][j][0][r] + er + hr);
        float zz = sigm(acc[i][j][1][r] + ez + hz);
        float nn = tanh_fast(acc[i][j][2][r] + en + rr * hnn);
        float hv = (1.0f - zz) * nn + zz * hprev[(size_t)m * 512 + n];
        hout32[(size_t)m * 512 + n] = hv;
        hout16[(size_t)m * 512 + n] = (f16)hv;
      }
    }
}

// ---------------- encoder step: gh GEMM (3 chunks) + fused gate, both dirs ----------------
__global__ __launch_bounds__(256) void k_enc_step(const f16* h16base, const f16* Whh,
                                                  const float* tabf, const float* tabb,
                                                  const float* bhhf, const float* bhhb,
                                                  const int* tgts, const float* h32base,
                                                  float* h32out, f16* h16out, f16* enc_out,
                                                  int t, int cur) {
  int n0 = blockIdx.x * 64, m0 = blockIdx.y * 64, dir = blockIdx.z;
  int tid = threadIdx.x, lane = tid & 63, w = tid >> 6, wm = w >> 1, wn = w & 1;
  const f16* A = h16base + dir * 65536 + cur * 32768;
  const f16* W = Whh + (size_t)dir * 768 * 256;
  f32x4 acc[2][2][3] = {};
  gemm_core<3>(A, 256, W, 256, 256, 256, m0, n0, lane, wm, wn, acc);
  int sidx = dir ? (S_ - 1 - t) : t;
  const float* bh  = dir ? bhhb : bhhf;
  const float* tb  = dir ? tabb : tabf;
  const float* h32 = h32base + dir * 65536 + cur * 32768;
  float* ho32      = h32out + dir * 65536;
  f16*   ho16      = h16out + dir * 65536;
#pragma unroll
  for (int i = 0; i < 2; i++)
#pragma unroll
    for (int j = 0; j < 2; j++) {
      int mb = m0 + wm * 32 + i * 16 + ((lane >> 4) << 2);
      int n  = n0 + wn * 32 + j * 16 + (lane & 15);
#pragma unroll
      for (int r = 0; r < 4; r++) {
        int b = mb + r;
        int tok = tgts[b * S_ + sidx];
        const float* row = tb + (size_t)tok * 768;
        float hr  = acc[i][j][0][r] + bh[n];
        float hz  = acc[i][j][1][r] + bh[n + 256];
        float hnn = acc[i][j][2][r] + bh[n + 512];
        float rr = sigm(row[n] + hr);
        float zz = sigm(row[n + 256] + hz);
        float nn = tanh_fast(row[n + 512] + rr * hnn);
        float hv = (1.0f - zz) * nn + zz * h32[b * 256 + n];
        ho32[b * 256 + n] = hv;
        ho16[b * 256 + n] = (f16)hv;
        enc_out[((size_t)b * S_ + sidx) * 512 + dir * 256 + n] = (f16)hv;
      }
    }
}

// ---------------- attention: scores + softmax + ctx ----------------
__global__ __launch_bounds__(256) void k_att(const float* CA, const f16* enc_att,
                                             const f16* enc_out, const float* av,
                                             float* ctx32, f16* ctx16) {
  int b = blockIdx.x;
  __shared__ float hq[512];
  __shared__ float vs[512];
  __shared__ float sc[128];
  __shared__ float red[8];
  int tid = threadIdx.x, w = tid >> 6, lane = tid & 63;
  for (int d = tid; d < 512; d += 256) {
    hq[d] = CA[(size_t)b * 5120 + d];
    vs[d] = av[d];
  }
  __syncthreads();
  for (int i = 0; i < 30; i++) {
    int s = w + 4 * i;
    f16x8 e = ((const f16x8*)(enc_att + ((size_t)b * S_ + s) * 512))[lane];
    int d0 = lane * 8;
    float a = 0.0f;
#pragma unroll
    for (int q = 0; q < 8; q++) a += vs[d0 + q] * tanh_fast((float)e[q] + hq[d0 + q]);
    a = wred_sum(a);
    if (lane == 0) sc[s] = a;
  }
  __syncthreads();
  float x = (tid < S_) ? sc[tid] : -1e30f;
  float mx = wred_max(x);
  if (lane == 0) red[w] = mx;
  __syncthreads();
  mx = fmaxf(fmaxf(red[0], red[1]), fmaxf(red[2], red[3]));
  float e = (tid < S_) ? __expf(x - mx) : 0.0f;
  float sm = wred_sum(e);
  if (lane == 0) red[4 + w] = sm;
  __syncthreads();
  float inv = 1.0f / (red[4] + red[5] + red[6] + red[7]);
  if (tid < S_) sc[tid] = e * inv;
  __syncthreads();
  for (int h = tid; h < 512; h += 256) {
    float cacc = 0.0f;
    const f16* eo = enc_out + (size_t)b * S_ * 512 + h;
#pragma unroll 4
    for (int s = 0; s < S_; s++) cacc = fmaf(sc[s], (float)eo[(size_t)s * 512], cacc);
    ctx32[b * 512 + h] = cacc;
    ctx16[b * 512 + h] = (f16)cacc;
  }
}

// ---------------- batched log_softmax over logits [15360][128] ----------------
__global__ __launch_bounds__(256) void k_lsm(const float* lg, float* out) {
  int row = blockIdx.x * 4 + (threadIdx.x >> 6);  // row = t*128 + b
  int lane = threadIdx.x & 63;
  const float* L = lg + (size_t)row * 128;
  float x1 = (lane < VCMP) ? L[lane] : -1e30f;
  float x2 = (lane + 64 < VCMP) ? L[lane + 64] : -1e30f;
  float mx = wred_max(fmaxf(x1, x2));
  float e = ((lane < VCMP) ? __expf(x1 - mx) : 0.0f) +
            ((lane + 64 < VCMP) ? __expf(x2 - mx) : 0.0f);
  float sm = wred_sum(e);
  float lse = mx + logf(sm);
  int t = row >> 7, b = row & 127;
  float* o = out + ((size_t)b * T_ + t) * VCMP;
  if (lane < VCMP) o[lane] = x1 - lse;
  if (lane + 64 < VCMP) o[lane + 64] = x2 - lse;
}

// ---------------- host ----------------
extern "C" void kernel_launch(void* const* d_in, const int* in_sizes, int n_in,
                              void* d_out, int out_size, void* d_ws, size_t ws_size,
                              hipStream_t stream) {
  (void)in_sizes; (void)n_in; (void)out_size; (void)ws_size;
  const int*   tgts    = (const int*)d_in[0];
  const int*   cmps    = (const int*)d_in[1];
  const float* emb_enc = (const float*)d_in[2];
  const float* eWih_f  = (const float*)d_in[3];
  const float* eWhh_f  = (const float*)d_in[4];
  const float* ebih_f  = (const float*)d_in[5];
  const float* ebhh_f  = (const float*)d_in[6];
  const float* eWih_b  = (const float*)d_in[7];
  const float* eWhh_b  = (const float*)d_in[8];
  const float* ebih_b  = (const float*)d_in[9];
  const float* ebhh_b  = (const float*)d_in[10];
  const float* emb_dec = (const float*)d_in[11];
  const float* attn_W  = (const float*)d_in[12];
  const float* attn_b  = (const float*)d_in[13];
  const float* attn_v  = (const float*)d_in[14];
  const float* dWih0   = (const float*)d_in[15];
  const float* dWhh0   = (const float*)d_in[16];
  const float* dbih0   = (const float*)d_in[17];
  const float* dbhh0   = (const float*)d_in[18];
  const float* dWih1   = (const float*)d_in[19];
  const float* dWhh1   = (const float*)d_in[20];
  const float* dbih1   = (const float*)d_in[21];
  const float* dbhh1   = (const float*)d_in[22];
  const float* dWih2   = (const float*)d_in[23];
  const float* dWhh2   = (const float*)d_in[24];
  const float* dbih2   = (const float*)d_in[25];
  const float* dbhh2   = (const float*)d_in[26];
  const float* out_W   = (const float*)d_in[27];
  const float* out_b   = (const float*)d_in[28];
  float* out = (float*)d_out;
  float* ws  = (float*)d_ws;

  float* tabF     = ws + OFF_TAB_F;
  float* tabB     = ws + OFF_TAB_B;
  float* tabD     = ws + OFF_TAB_D;
  float* henc32   = ws + OFF_HENC32;
  f16*   henc16   = (f16*)(ws + OFF_HENC16);
  float* hdec32   = ws + OFF_HDEC32;
  f16*   hdec16   = (f16*)(ws + OFF_HDEC16);
  float* CA       = ws + OFF_CA;
  float* ctx32    = ws + OFF_CTX32;
  f16*   ctx16    = (f16*)(ws + OFF_CTX16);
  f16*   H2all    = (f16*)(ws + OFF_H2ALL);
  f16*   encout16 = (f16*)(ws + OFF_ENCOUT);
  f16*   encatt16 = (f16*)(ws + OFF_ENCATT);
  float* logits   = ws + OFF_LOGITS;
  f16*   Wcat     = (f16*)(ws + OFF_WCAT);
  f16*   Wih0c    = (f16*)(ws + OFF_WIH0C);
  f16*   Wih1h    = (f16*)(ws + OFF_WIH1);
  f16*   Wih2h    = (f16*)(ws + OFF_WIH2);
  f16*   Ueh      = (f16*)(ws + OFF_UE);
  f16*   eWhhh    = (f16*)(ws + OFF_EWHH);
  f16*   oWh      = (f16*)(ws + OFF_OW);

  // ---- prep: zeros, tables, fp16 weight conversion ----
  k_zero<<<(720896 + 255) / 256, 256, 0, stream>>>(ws + OFF_HENC32, 720896);   // all h states
  k_zero<<<(32768 + 255) / 256, 256, 0, stream>>>(ws + OFF_H2ALL, 32768);      // H2all slot 0
  k_zero<<<(32768 + 255) / 256, 256, 0, stream>>>(ws + OFF_OW, 32768);         // oW pad
  k_embgi_enc<<<dim3(300, 2), 256, 0, stream>>>(emb_enc, eWih_f, ebih_f, eWih_b, ebih_b, tabF, tabB);
  k_embgi_dec<<<600, 256, 0, stream>>>(emb_dec, dWih0, dbih0, tabD);
  auto cvt = [&](const float* src, f16* dst, int rows, int cols, int ldsrc, int off) {
    int n = rows * cols;
    k_cvt<<<(n + 255) / 256, 256, 0, stream>>>(src, dst, rows, cols, ldsrc, off);
  };
  cvt(attn_W, Wcat,               512, 512, 1024, 0);    // Ua
  cvt(dWhh0,  Wcat + 512 * 512,  1536, 512, 512, 0);
  cvt(dWhh1,  Wcat + 2048 * 512, 1536, 512, 512, 0);
  cvt(dWhh2,  Wcat + 3584 * 512, 1536, 512, 512, 0);
  cvt(dWih0,  Wih0c,             1536, 512, 640, 128);
  cvt(dWih1,  Wih1h,             1536, 512, 512, 0);
  cvt(dWih2,  Wih2h,             1536, 512, 512, 0);
  cvt(attn_W, Ueh,                512, 512, 1024, 512);
  cvt(eWhh_f, eWhhh,              768, 256, 256, 0);
  cvt(eWhh_b, eWhhh + 768 * 256,  768, 256, 256, 0);
  cvt(out_W,  oWh,                100, 512, 512, 0);

  // ---- encoder: 120 steps, one fused kernel per step (both dirs) ----
  for (int t = 0; t < S_; t++) {
    int cur = t & 1, nxt = cur ^ 1;
    k_enc_step<<<dim3(4, 2, 2), 256, 0, stream>>>(
        henc16, eWhhh, tabF, tabB, ebhh_f, ebhh_b, tgts, henc32,
        henc32 + nxt * 32768, henc16 + nxt * 32768, encout16, t, cur);
  }
  // decoder h0 init from final enc states (pp=0 after even #steps)
  k_h0init<<<256, 256, 0, stream>>>(henc32, henc32 + 65536, hdec32, hdec16);

  // ---- hoisted: enc_att = enc_out @ Ue^T + attn_b (f16 out) ----
  k_gemm_bias<true><<<dim3(8, 240), 256, 0, stream>>>(encout16, 512, Ueh, 512, attn_b, 512,
                                                      encatt16, 512, 512);

  // ---- decoder: 120 steps x 5 kernels ----
  for (int t = 0; t < T_; t++) {
    int cur = t & 1, nxt = cur ^ 1;
    const f16* h0c16 = hdec16 + cur * 131072;
    const f16* h1c16 = hdec16 + cur * 131072 + 65536;
    const f16* h2c16 = H2all + (size_t)t * 65536;
    k_phaseA<<<dim3(80, 2), 256, 0, stream>>>(h0c16, h1c16, h2c16, Wcat, CA);
    k_att<<<128, 256, 0, stream>>>(CA, encatt16, encout16, attn_v, ctx32, ctx16);
    k_dec_layer<<<dim3(8, 2), 256, 0, stream>>>(
        ctx16, Wih0c, CA, 512, tabD, cmps, t, nullptr, dbhh0,
        hdec32 + cur * 196608, hdec32 + nxt * 196608, hdec16 + nxt * 131072);
    k_dec_layer<<<dim3(8, 2), 256, 0, stream>>>(
        hdec16 + nxt * 131072, Wih1h, CA, 2048, nullptr, nullptr, t, dbih1, dbhh1,
        hdec32 + cur * 196608 + 65536, hdec32 + nxt * 196608 + 65536,
        hdec16 + nxt * 131072 + 65536);
    k_dec_layer<<<dim3(8, 2), 256, 0, stream>>>(
        hdec16 + nxt * 131072 + 65536, Wih2h, CA, 3584, nullptr, nullptr, t, dbih2, dbhh2,
        hdec32 + cur * 196608 + 131072, hdec32 + nxt * 196608 + 131072,
        H2all + (size_t)(t + 1) * 65536);
  }

  // ---- batched output projection + log_softmax ----
  k_gemm_bias<false><<<dim3(2, 240), 256, 0, stream>>>(H2all + 65536, 512, oWh, 512, out_b, VCMP,
                                                       logits, 128, 512);
  k_lsm<<<3840, 256, 0, stream>>>(logits, out);
}